// Round 1
// baseline (10825.563 us; speedup 1.0000x reference)
//
#include <hip/hip_runtime.h>
#include <hip/hip_bf16.h>
#include <math.h>

#define SEQL 2048
#define EDIM 256
#define HID 256
#define G4 1024
#define HCAT 512
#define TT 11
#define START_TAG 9
#define STOP_TAG 10
#define NEGV -10000.0f
#define ALPHA_LR 0.2f
#define VCH 64
#define VCS 32

__device__ __forceinline__ float sigf(float x) { return 1.0f / (1.0f + __expf(-x)); }
__device__ __forceinline__ float tanhfast(float x) { return 2.0f / (1.0f + __expf(-2.0f * x)) - 1.0f; }

// ---------------- embedding gather ----------------
__global__ void embed_k(const int* __restrict__ sent, const float* __restrict__ emb,
                        float* __restrict__ x) {
    int idx = blockIdx.x * 256 + threadIdx.x;     // 2048*256 total
    int t = idx >> 8, e = idx & 255;
    x[idx] = emb[(size_t)sent[t] * EDIM + e];
}

// ---------------- GEMM: C[M,N] = A[M,K] * B[N,K]^T + bias ----------------
__global__ __launch_bounds__(256) void gemm_nt(const float* __restrict__ A,
                                               const float* __restrict__ B,
                                               const float* __restrict__ bias,
                                               float* __restrict__ C,
                                               int M, int N, int K) {
    __shared__ float As[16][68];
    __shared__ float Bs[16][68];
    int tid = threadIdx.x;
    int tx = tid & 15, ty = tid >> 4;
    int m0 = blockIdx.y * 64, n0 = blockIdx.x * 64;
    int lr = tid >> 2;
    int lc = (tid & 3) * 4;
    float acc[4][4] = {};
    for (int k0 = 0; k0 < K; k0 += 16) {
        float4 av = *(const float4*)(A + (size_t)(m0 + lr) * K + k0 + lc);
        float4 bv = make_float4(0.f, 0.f, 0.f, 0.f);
        if (n0 + lr < N) bv = *(const float4*)(B + (size_t)(n0 + lr) * K + k0 + lc);
        As[lc + 0][lr] = av.x; As[lc + 1][lr] = av.y; As[lc + 2][lr] = av.z; As[lc + 3][lr] = av.w;
        Bs[lc + 0][lr] = bv.x; Bs[lc + 1][lr] = bv.y; Bs[lc + 2][lr] = bv.z; Bs[lc + 3][lr] = bv.w;
        __syncthreads();
#pragma unroll
        for (int kk = 0; kk < 16; ++kk) {
            float4 a4 = *(const float4*)&As[kk][ty * 4];
            float4 b4 = *(const float4*)&Bs[kk][tx * 4];
            float aa[4] = {a4.x, a4.y, a4.z, a4.w};
            float bb[4] = {b4.x, b4.y, b4.z, b4.w};
#pragma unroll
            for (int i = 0; i < 4; ++i)
#pragma unroll
                for (int j = 0; j < 4; ++j) acc[i][j] += aa[i] * bb[j];
        }
        __syncthreads();
    }
#pragma unroll
    for (int i = 0; i < 4; ++i) {
        int m = m0 + ty * 4 + i;
#pragma unroll
        for (int j = 0; j < 4; ++j) {
            int n = n0 + tx * 4 + j;
            if (n < N) {
                float v = acc[i][j];
                if (bias) v += bias[n];
                C[(size_t)m * N + n] = v;
            }
        }
    }
}

// ---------------- GEMM: C[M,N] = A[M,K] * B[K,N], optional rowdiv + ELU ----------------
__global__ __launch_bounds__(256) void gemm_nn(const float* __restrict__ A,
                                               const float* __restrict__ B,
                                               float* __restrict__ C,
                                               const float* __restrict__ rowdiv,
                                               int do_elu, int M, int N, int K) {
    __shared__ float As[16][68];
    __shared__ float Bs[16][68];
    int tid = threadIdx.x;
    int tx = tid & 15, ty = tid >> 4;
    int m0 = blockIdx.y * 64, n0 = blockIdx.x * 64;
    int lr = tid >> 2;
    int lc = (tid & 3) * 4;
    int br = tid >> 4;
    int bc = (tid & 15) * 4;
    float acc[4][4] = {};
    for (int k0 = 0; k0 < K; k0 += 16) {
        float4 av = *(const float4*)(A + (size_t)(m0 + lr) * K + k0 + lc);
        float4 bv = *(const float4*)(B + (size_t)(k0 + br) * N + n0 + bc);
        As[lc + 0][lr] = av.x; As[lc + 1][lr] = av.y; As[lc + 2][lr] = av.z; As[lc + 3][lr] = av.w;
        *(float4*)&Bs[br][bc] = bv;
        __syncthreads();
#pragma unroll
        for (int kk = 0; kk < 16; ++kk) {
            float4 a4 = *(const float4*)&As[kk][ty * 4];
            float4 b4 = *(const float4*)&Bs[kk][tx * 4];
            float aa[4] = {a4.x, a4.y, a4.z, a4.w};
            float bb[4] = {b4.x, b4.y, b4.z, b4.w};
#pragma unroll
            for (int i = 0; i < 4; ++i)
#pragma unroll
                for (int j = 0; j < 4; ++j) acc[i][j] += aa[i] * bb[j];
        }
        __syncthreads();
    }
#pragma unroll
    for (int i = 0; i < 4; ++i) {
        int m = m0 + ty * 4 + i;
        float rd = rowdiv ? rowdiv[m] : 1.0f;
#pragma unroll
        for (int j = 0; j < 4; ++j) {
            int n = n0 + tx * 4 + j;
            float v = acc[i][j];
            if (rowdiv) v /= rd;
            if (do_elu) v = v > 0.f ? v : (__expf(v) - 1.f);
            C[(size_t)m * N + n] = v;
        }
    }
}

// ---------------- BiLSTM recurrent scan ----------------
// 16 blocks: dir = blk>>3 (0 fwd, 1 bwd), sub-block sb = blk&7 owns hidden units [sb*32, sb*32+32).
// whh slice (128 rows x 256) held in registers (32 VGPR/thread). h exchanged via device-scope atomics.
__global__ __launch_bounds__(1024) void lstm_scan(const float* __restrict__ xin_f,
                                                  const float* __restrict__ xin_b,
                                                  const float* __restrict__ whh_f,
                                                  const float* __restrict__ whh_b,
                                                  const float* __restrict__ hc,
                                                  float* __restrict__ out,
                                                  float* h_glob, int* prog) {
    int tid = threadIdx.x;
    int blk = blockIdx.x;
    int dir = blk >> 3;
    int sb = blk & 7;
    int u0 = sb * 32;
    const float* xin = dir ? xin_b : xin_f;
    const float* whh = dir ? whh_b : whh_f;

    int row = tid & 127;   // local gate-row
    int q = tid >> 7;      // k-chunk 0..7
    int g = row >> 5;
    int j = row & 31;
    int rg = g * HID + u0 + j;

    float4 w[8];
    const float* wrow = whh + (size_t)rg * HID + q * 32;
#pragma unroll
    for (int m = 0; m < 8; ++m) w[m] = *(const float4*)(wrow + 4 * m);

    __shared__ float h_lds[256];
    __shared__ float zp[8 * 128];
    __shared__ float z_lds[128];

    if (tid < 256) h_lds[tid] = hc[dir * 512 + tid];
    float c = 0.f;
    if (tid < 32) c = hc[dir * 512 + 256 + u0 + tid];
    __syncthreads();

    for (int s = 0; s < SEQL; ++s) {
        int t = dir ? (SEQL - 1 - s) : s;
        float xv = 0.f;
        if (tid < 128) xv = xin[(size_t)t * G4 + g * HID + u0 + j];

        const float4* h4 = (const float4*)(h_lds + q * 32);
        float acc = 0.f;
#pragma unroll
        for (int m = 0; m < 8; ++m) {
            float4 hv = h4[m];
            acc += w[m].x * hv.x + w[m].y * hv.y + w[m].z * hv.z + w[m].w * hv.w;
        }
        zp[q * 128 + row] = acc;
        __syncthreads();
        if (tid < 128) {
            float z = xv;
#pragma unroll
            for (int qq = 0; qq < 8; ++qq) z += zp[qq * 128 + tid];
            z_lds[tid] = z;
        }
        __syncthreads();
        if (tid < 32) {
            float zi = z_lds[tid], zf = z_lds[32 + tid], zg = z_lds[64 + tid], zo = z_lds[96 + tid];
            float ig = sigf(zi), fg = sigf(zf), gg = tanhfast(zg), og = sigf(zo);
            c = fg * c + ig * gg;
            float hn = og * tanhfast(c);
            out[(size_t)t * HCAT + dir * HID + u0 + tid] = hn;
            __hip_atomic_store(&h_glob[dir * HID + u0 + tid], hn, __ATOMIC_RELAXED,
                               __HIP_MEMORY_SCOPE_AGENT);
        }
        __syncthreads();
        if (tid == 0) {
            __threadfence();
            __hip_atomic_store(&prog[dir * 8 + sb], s + 1, __ATOMIC_RELEASE,
                               __HIP_MEMORY_SCOPE_AGENT);
        }
        if (tid < 8) {
            while (__hip_atomic_load(&prog[dir * 8 + tid], __ATOMIC_ACQUIRE,
                                     __HIP_MEMORY_SCOPE_AGENT) < s + 1) {
                __builtin_amdgcn_s_sleep(1);
            }
        }
        __syncthreads();
        if (tid < 256)
            h_lds[tid] = __hip_atomic_load(&h_glob[dir * HID + tid], __ATOMIC_RELAXED,
                                           __HIP_MEMORY_SCOPE_AGENT);
        __syncthreads();
    }
}

// ---------------- GAT helpers ----------------
__global__ void gat_scores(const float* __restrict__ Wh, const float* __restrict__ a,
                           float* __restrict__ s1, float* __restrict__ s2) {
    int i = blockIdx.x;
    int lane = threadIdx.x;  // 64
    const float* rowp = Wh + (size_t)i * HCAT;
    float p1 = 0.f, p2 = 0.f;
    for (int k = lane; k < HCAT; k += 64) {
        float w = rowp[k];
        p1 += w * a[k];
        p2 += w * a[HCAT + k];
    }
    for (int off = 32; off; off >>= 1) {
        p1 += __shfl_down(p1, off, 64);
        p2 += __shfl_down(p2, off, 64);
    }
    if (lane == 0) { s1[i] = p1; s2[i] = p2; }
}

__global__ void reduce_max_k(const float* __restrict__ s2, float* __restrict__ outv) {
    __shared__ float red[256];
    int tid = threadIdx.x;
    float m = -INFINITY;
    for (int k = tid; k < SEQL; k += 256) m = fmaxf(m, s2[k]);
    red[tid] = m;
    __syncthreads();
    for (int off = 128; off; off >>= 1) {
        if (tid < off) red[tid] = fmaxf(red[tid], red[tid + off]);
        __syncthreads();
    }
    if (tid == 0) outv[0] = red[0];
}

__global__ void gat_p(const float* __restrict__ s1, const float* __restrict__ s2,
                      const float* __restrict__ s2m, float* __restrict__ P,
                      float* __restrict__ Z) {
    int i = blockIdx.x;
    int tid = threadIdx.x;  // 256
    float base = s1[i];
    float m = base + s2m[0];
    m = m > 0.f ? m : ALPHA_LR * m;  // leaky_relu monotonic -> exact row max
    float zs = 0.f;
    for (int jj = tid; jj < SEQL; jj += 256) {
        float e = base + s2[jj];
        e = e > 0.f ? e : ALPHA_LR * e;
        float p = __expf(e - m);
        P[(size_t)i * SEQL + jj] = p;
        zs += p;
    }
    __shared__ float red[256];
    red[tid] = zs;
    __syncthreads();
    for (int off = 128; off; off >>= 1) {
        if (tid < off) red[tid] += red[tid + off];
        __syncthreads();
    }
    if (tid == 0) Z[i] = red[0];
}

// ---------------- Viterbi (max-plus parallel scan) ----------------
__global__ void vit_chunkA(const float* __restrict__ feats, const float* __restrict__ trans,
                           float* __restrict__ chunkA) {
    int c = blockIdx.x;
    int tid = threadIdx.x;  // 128
    __shared__ float Acur[121], tr[121];
    if (tid < 121) tr[tid] = trans[tid];
    __syncthreads();
    int n = tid / 11, p = tid % 11;
    int t0 = c * VCS;
    if (tid < 121) Acur[tid] = tr[tid] + feats[t0 * TT + n];
    __syncthreads();
    for (int t = t0 + 1; t < t0 + VCS; ++t) {
        float v = -INFINITY;
        if (tid < 121) {
            float ft = feats[t * TT + n];
#pragma unroll
            for (int k = 0; k < 11; ++k) v = fmaxf(v, tr[n * 11 + k] + Acur[k * 11 + p]);
            v += ft;
        }
        __syncthreads();
        if (tid < 121) Acur[tid] = v;
        __syncthreads();
    }
    if (tid < 121) chunkA[c * 121 + tid] = Acur[tid];
}

__global__ void vit_prefix(const float* __restrict__ chunkA, float* __restrict__ fvstart) {
    int tid = threadIdx.x;  // 128
    __shared__ float fv[11];
    if (tid < 11) fv[tid] = (tid == START_TAG) ? 0.f : NEGV;
    __syncthreads();
    if (tid < 11) fvstart[tid] = fv[tid];
    for (int c = 0; c < VCH; ++c) {
        float v = -INFINITY;
        if (tid < 11) {
            for (int p = 0; p < 11; ++p) v = fmaxf(v, chunkA[c * 121 + tid * 11 + p] + fv[p]);
        }
        __syncthreads();
        if (tid < 11) { fv[tid] = v; fvstart[(c + 1) * TT + tid] = v; }
        __syncthreads();
    }
}

__global__ void vit_chunkC(const float* __restrict__ feats, const float* __restrict__ trans,
                           const float* __restrict__ fvstart, int* __restrict__ bp,
                           float* __restrict__ fvfinal) {
    int c = blockIdx.x;
    int tid = threadIdx.x;  // 128
    __shared__ float fv[11], tr[121], sc[121], mx[11];
    if (tid < 121) tr[tid] = trans[tid];
    if (tid < 11) fv[tid] = fvstart[c * TT + tid];
    __syncthreads();
    int t0 = c * VCS;
    for (int t = t0; t < t0 + VCS; ++t) {
        if (tid < 121) sc[tid] = fv[tid % 11] + tr[tid];
        __syncthreads();
        if (tid < 11) {
            float best = -INFINITY;
            int bi = 0;
            for (int k = 0; k < 11; ++k) {
                float v = sc[tid * 11 + k];
                if (v > best) { best = v; bi = k; }
            }
            bp[t * TT + tid] = bi;
            mx[tid] = best + feats[t * TT + tid];
        }
        __syncthreads();
        if (tid < 11) fv[tid] = mx[tid];
        __syncthreads();
    }
    if (c == VCH - 1 && tid < 11) fvfinal[tid] = fv[tid];
}

__global__ __launch_bounds__(1024) void vit_back(const int* __restrict__ bp,
                                                 const float* __restrict__ fvfinal,
                                                 const float* __restrict__ trans,
                                                 float* __restrict__ outp) {
    __shared__ unsigned char bufA[SEQL * TT];
    __shared__ unsigned char bufB[SEQL * TT];
    __shared__ int bestIdx;
    int tid = threadIdx.x;
    for (int idx = tid; idx < SEQL * TT; idx += 1024) {
        int t = idx / TT, n = idx - t * TT;
        bufA[idx] = (t < SEQL - 1) ? (unsigned char)bp[(t + 1) * TT + n] : (unsigned char)n;
    }
    __syncthreads();
    unsigned char* a = bufA;
    unsigned char* b = bufB;
    for (int len = 1; len < SEQL - 1; len <<= 1) {
        for (int idx = tid; idx < SEQL * TT; idx += 1024) {
            int t = idx / TT, n = idx - t * TT;
            int m = (t + len <= SEQL - 1) ? (int)a[(t + len) * TT + n] : n;
            b[t * TT + n] = a[t * TT + m];
        }
        __syncthreads();
        unsigned char* tmp = a; a = b; b = tmp;
        __syncthreads();
    }
    if (tid == 0) {
        float bs = -INFINITY;
        int bi = 0;
        for (int p = 0; p < 11; ++p) {
            float v = fvfinal[p] + trans[STOP_TAG * 11 + p];
            if (v > bs) { bs = v; bi = p; }
        }
        outp[0] = bs;
        bestIdx = bi;
    }
    __syncthreads();
    int best = bestIdx;
    for (int t = tid; t < SEQL; t += 1024) outp[1 + t] = (float)a[t * TT + best];
}

// ---------------- host launcher ----------------
extern "C" void kernel_launch(void* const* d_in, const int* in_sizes, int n_in,
                              void* d_out, int out_size, void* d_ws, size_t ws_size,
                              hipStream_t stream) {
    const int* sent = (const int*)d_in[0];
    const float* emb = (const float*)d_in[1];
    const float* w1f = (const float*)d_in[2];
    const float* u1f = (const float*)d_in[3];
    const float* b1f = (const float*)d_in[4];
    const float* w1b = (const float*)d_in[5];
    const float* u1b = (const float*)d_in[6];
    const float* b1b = (const float*)d_in[7];
    const float* hc1 = (const float*)d_in[8];
    const float* g1W = (const float*)d_in[9];
    const float* g1a = (const float*)d_in[10];
    const float* g2W = (const float*)d_in[11];
    const float* g2a = (const float*)d_in[12];
    const float* w2f = (const float*)d_in[13];
    const float* u2f = (const float*)d_in[14];
    const float* b2f = (const float*)d_in[15];
    const float* w2b = (const float*)d_in[16];
    const float* u2b = (const float*)d_in[17];
    const float* b2b = (const float*)d_in[18];
    const float* hc2 = (const float*)d_in[19];
    const float* wtag = (const float*)d_in[20];
    const float* btag = (const float*)d_in[21];
    const float* trans = (const float*)d_in[22];

    float* ws = (float*)d_ws;
    float* x = ws;                      // 524288
    float* R1 = x + 524288;             // 4194304 floats (xin_f+xin_b | P)
    float* xin_f = R1;
    float* xin_b = R1 + 2097152;
    float* P = R1;
    float* h1cat = R1 + 4194304;        // 1048576 (h1cat | g2)
    float* Wh = h1cat + 1048576;        // 1048576
    float* g1 = Wh + 1048576;           // 1048576 (g1 | h2cat)
    float* s1 = g1 + 1048576;           // 2048
    float* s2 = s1 + 2048;              // 2048
    float* Zr = s2 + 2048;              // 2048
    float* s2m = Zr + 2048;             // 16
    float* hglob = s2m + 16;            // 512
    float* feats = hglob + 512;         // 22528
    float* chA = feats + 22528;         // 7744
    float* fvst = chA + 7744;           // 720
    float* fvfin = fvst + 720;          // 16
    int* prog = (int*)(fvfin + 16);     // 32 ints
    int* bp = prog + 32;                // 22528 ints

    hipMemsetAsync(prog, 0, 32 * sizeof(int), stream);

    embed_k<<<SEQL, 256, 0, stream>>>(sent, emb, x);

    // BiLSTM 1 input projections
    gemm_nt<<<dim3(16, 32), 256, 0, stream>>>(x, w1f, b1f, xin_f, SEQL, G4, EDIM);
    gemm_nt<<<dim3(16, 32), 256, 0, stream>>>(x, w1b, b1b, xin_b, SEQL, G4, EDIM);
    lstm_scan<<<16, 1024, 0, stream>>>(xin_f, xin_b, u1f, u1b, hc1, h1cat, hglob, prog);

    // GAT 1
    gemm_nn<<<dim3(8, 32), 256, 0, stream>>>(h1cat, g1W, Wh, nullptr, 0, SEQL, HCAT, HCAT);
    gat_scores<<<SEQL, 64, 0, stream>>>(Wh, g1a, s1, s2);
    reduce_max_k<<<1, 256, 0, stream>>>(s2, s2m);
    gat_p<<<SEQL, 256, 0, stream>>>(s1, s2, s2m, P, Zr);
    gemm_nn<<<dim3(8, 32), 256, 0, stream>>>(P, Wh, g1, Zr, 1, SEQL, HCAT, SEQL);

    // GAT 2
    gemm_nn<<<dim3(8, 32), 256, 0, stream>>>(g1, g2W, Wh, nullptr, 0, SEQL, HCAT, HCAT);
    gat_scores<<<SEQL, 64, 0, stream>>>(Wh, g2a, s1, s2);
    reduce_max_k<<<1, 256, 0, stream>>>(s2, s2m);
    gat_p<<<SEQL, 256, 0, stream>>>(s1, s2, s2m, P, Zr);
    float* g2v = h1cat;  // reuse
    gemm_nn<<<dim3(8, 32), 256, 0, stream>>>(P, Wh, g2v, Zr, 1, SEQL, HCAT, SEQL);

    // BiLSTM 2
    gemm_nt<<<dim3(16, 32), 256, 0, stream>>>(g2v, w2f, b2f, xin_f, SEQL, G4, HCAT);
    gemm_nt<<<dim3(16, 32), 256, 0, stream>>>(g2v, w2b, b2b, xin_b, SEQL, G4, HCAT);
    float* h2cat = g1;  // reuse
    lstm_scan<<<16, 1024, 0, stream>>>(xin_f, xin_b, u2f, u2b, hc2, h2cat, hglob, prog + 16);

    // tag projection + Viterbi
    gemm_nt<<<dim3(1, 32), 256, 0, stream>>>(h2cat, wtag, btag, feats, SEQL, TT, HCAT);
    vit_chunkA<<<VCH, 128, 0, stream>>>(feats, trans, chA);
    vit_prefix<<<1, 128, 0, stream>>>(chA, fvst);
    vit_chunkC<<<VCH, 128, 0, stream>>>(feats, trans, fvst, bp, fvfin);
    vit_back<<<1, 1024, 0, stream>>>(bp, fvfin, trans, (float*)d_out);
}